// Round 1
// baseline (260.669 us; speedup 1.0000x reference)
//
#include <hip/hip_runtime.h>
#include <cstddef>

#define D 128

static constexpr float A_SCALE = 0.1f;
static constexpr float B_SCALE = 0.1f;

__device__ __forceinline__ float4 ldf4(const float* p) {
    return *reinterpret_cast<const float4*>(p);
}

// ---------------------------------------------------------------------------
// Pass 1: per-row dots + global reduction partials.
// Wave layout: 64 lanes = 2 rows; lane handles 4 cols (float4). 5-level
// shfl_xor butterfly stays within each 32-lane half.
// User side dots (s = j):   j0: xe.w_vec[b,0]=a_xx  (store slot b, accum k=b)
//                           j1: xe.w_vec[b,1]=a_xyx (store slot 3+b)
//                           j2: xe.w_vec[b,2]=a_yxy (accum k=3+b)
// Item side dots (s = j+1): j0: ye.w_vec[b,1]=a_xyy (accum k=b)
//                           j1: ye.w_vec[b,2]=a_yxx (store slot 3+b)
//                           j2: ye.w_vec[b,3]=a_yy  (store slot b, accum k=3+b)
// Partials layout: partial[t][blk], t in [0,768) = k*128+d  (coalesced combine)
// ---------------------------------------------------------------------------
template<bool IS_USER>
__global__ __launch_bounds__(256) void pass1_kernel(
    const float* __restrict__ emb, const int* __restrict__ ids, int nrows,
    const float* __restrict__ w_vec, const float* __restrict__ edge_emb,
    float* __restrict__ dots, float* __restrict__ partial, int nb)
{
    const int lane = threadIdx.x & 63;
    const int half = lane >> 5;
    const int li   = lane & 31;
    const int col  = li << 2;
    const int waveInBlk = threadIdx.x >> 6;
    const int halfId    = threadIdx.x >> 5;

    float wv[3][3][4];
#pragma unroll
    for (int b = 0; b < 3; ++b) {
#pragma unroll
        for (int j = 0; j < 3; ++j) {
            const int s = IS_USER ? j : (j + 1);
            float4 w = ldf4(w_vec + ((b * 4 + s) * D + col));
            wv[b][j][0] = w.x; wv[b][j][1] = w.y; wv[b][j][2] = w.z; wv[b][j][3] = w.w;
        }
    }
    float e[4];
    {
        float4 t = ldf4(edge_emb + col);
        e[0] = t.x * B_SCALE; e[1] = t.y * B_SCALE; e[2] = t.z * B_SCALE; e[3] = t.w * B_SCALE;
    }

    float acc[6][4];
#pragma unroll
    for (int k = 0; k < 6; ++k)
#pragma unroll
        for (int j = 0; j < 4; ++j) acc[k][j] = 0.f;

    const int pairs = (nrows + 1) >> 1;
    for (int p = blockIdx.x * 4 + waveInBlk; p < pairs; p += gridDim.x * 4) {
        const int row = p * 2 + half;
        const bool valid = row < nrows;
        float x0[4] = {0.f, 0.f, 0.f, 0.f};
        if (valid) {
            const int src = ids[row];
            float4 t = ldf4(emb + (size_t)src * D + col);
            x0[0] = t.x * A_SCALE; x0[1] = t.y * A_SCALE;
            x0[2] = t.z * A_SCALE; x0[3] = t.w * A_SCALE;
        }
        float xe[4];
#pragma unroll
        for (int j = 0; j < 4; ++j) xe[j] = x0[j] * e[j];

        float d[3][3];
#pragma unroll
        for (int b = 0; b < 3; ++b)
#pragma unroll
            for (int j = 0; j < 3; ++j) {
                float s = xe[0] * wv[b][j][0];
                s = fmaf(xe[1], wv[b][j][1], s);
                s = fmaf(xe[2], wv[b][j][2], s);
                s = fmaf(xe[3], wv[b][j][3], s);
                d[b][j] = s;
            }
#pragma unroll
        for (int m = 1; m <= 16; m <<= 1) {
#pragma unroll
            for (int b = 0; b < 3; ++b)
#pragma unroll
                for (int j = 0; j < 3; ++j)
                    d[b][j] += __shfl_xor(d[b][j], m, 64);
        }
        if (valid && li == 0) {
            float* dp = dots + (size_t)row * 6;
            if (IS_USER) {
                dp[0] = d[0][0]; dp[1] = d[1][0]; dp[2] = d[2][0];
                dp[3] = d[0][1]; dp[4] = d[1][1]; dp[5] = d[2][1];
            } else {
                dp[0] = d[0][2]; dp[1] = d[1][2]; dp[2] = d[2][2];
                dp[3] = d[0][1]; dp[4] = d[1][1]; dp[5] = d[2][1];
            }
        }
        if (valid) {
#pragma unroll
            for (int b = 0; b < 3; ++b) {
                const float c0 = d[b][0];
                const float c1 = d[b][2];
#pragma unroll
                for (int j = 0; j < 4; ++j) {
                    acc[b][j]     = fmaf(c0, x0[j], acc[b][j]);
                    acc[3 + b][j] = fmaf(c1, x0[j], acc[3 + b][j]);
                }
            }
        }
    }

    // Deterministic block reduce: each 32-lane half owns a private LDS slice.
    __shared__ float lds[8][6][D];
#pragma unroll
    for (int k = 0; k < 6; ++k) {
        float4 v;
        v.x = acc[k][0]; v.y = acc[k][1]; v.z = acc[k][2]; v.w = acc[k][3];
        *reinterpret_cast<float4*>(&lds[halfId][k][col]) = v;
    }
    __syncthreads();
    for (int t = threadIdx.x; t < 6 * D; t += 256) {
        const int k = t >> 7, dd = t & 127;
        float s = 0.f;
#pragma unroll
        for (int h = 0; h < 8; ++h) s += lds[h][k][dd];
        partial[(size_t)t * nb + blockIdx.x] = s;
    }
}

// ---------------------------------------------------------------------------
// Combine: one wave per (vector v, dim d) output; coalesced strided sum over
// nb block partials; fixed-order butterfly -> deterministic. R layout:
// R[0..2]=a_xx@x0, R[3..5]=a_yxy@x0, R[6..8]=a_xyy@y0, R[9..11]=a_yy@y0.
// ---------------------------------------------------------------------------
__global__ __launch_bounds__(256) void combine_kernel(
    const float* __restrict__ pu, const float* __restrict__ pi, int nb,
    float* __restrict__ R)
{
    const int w = blockIdx.x * 4 + (threadIdx.x >> 6);   // 0..1535
    const int lane = threadIdx.x & 63;
    const int v = w >> 7, dd = w & 127;
    const float* p = (v < 6) ? (pu + (size_t)(v * 128 + dd) * nb)
                             : (pi + (size_t)((v - 6) * 128 + dd) * nb);
    float s = 0.f;
    for (int i = lane; i < nb; i += 64) s += p[i];
#pragma unroll
    for (int m = 1; m <= 32; m <<= 1) s += __shfl_xor(s, m, 64);
    if (lane == 0) R[w] = s;
}

// ---------------------------------------------------------------------------
// gmat: 12 matvecs (R @ w_mat, folded constants) -> G; 3 edge rows -> d_out.
// G[0..2]=G1[b] (pairs a_xx), G[3..5]=G2[b] (pairs a_xyx),
// G[6..8]=H1[b] (pairs a_yy), G[9..11]=H2[b] (pairs a_yxx).
// ---------------------------------------------------------------------------
__global__ __launch_bounds__(128) void gmat_kernel(
    const float* __restrict__ R, const float* __restrict__ w_mat,
    const float* __restrict__ edge_w, const float* __restrict__ edge_emb,
    float* __restrict__ G, float* __restrict__ out_edge)
{
    const float mtl[3] = {0.5f, 0.3333333f, 0.1666667f};
    const int blk = blockIdx.x;
    const int d = threadIdx.x;
    if (blk < 12) {
        const int b = blk % 3;
        const int grp = blk / 3;          // 0:G1 1:G2 2:H1 3:H2
        int s, v;
        if      (grp == 0) { s = 0; v = b; }
        else if (grp == 1) { s = 1; v = 6 + b; }
        else if (grp == 2) { s = 3; v = 9 + b; }
        else               { s = 2; v = 3 + b; }
        const float* M = w_mat + (size_t)(b * 4 + s) * D * D;
        const float* r = R + v * D;
        float sum = 0.f;
        for (int k = 0; k < D; ++k) sum = fmaf(r[k], M[(size_t)k * D + d], sum);
        G[blk * D + d] = 0.25f * mtl[b] * sum;
    } else {
        const int b = blk - 12;
        const float* M = edge_w + (size_t)b * D * D;
        float sum = 0.f;
        for (int k = 0; k < D; ++k)
            sum = fmaf(edge_emb[k] * B_SCALE, M[(size_t)k * D + d], sum);
        out_edge[b * D + d] = 0.5f * (sum + edge_emb[d] * B_SCALE);
    }
}

// ---------------------------------------------------------------------------
// Pass 2: out[r,:] = 0.5*x0[r,:] + sum_b c[b]*G[b][:] + c[3+b]*G[3+b][:]
// ---------------------------------------------------------------------------
__global__ __launch_bounds__(256) void pass2_kernel(
    const float* __restrict__ emb, const int* __restrict__ ids, int nrows,
    const float* __restrict__ dots, const float* __restrict__ G,
    float* __restrict__ out)
{
    const int lane = threadIdx.x & 63;
    const int half = lane >> 5;
    const int li   = lane & 31;
    const int col  = li << 2;
    const int waveInBlk = threadIdx.x >> 6;

    float g[6][4];
#pragma unroll
    for (int k = 0; k < 6; ++k) {
        float4 t = ldf4(G + k * D + col);
        g[k][0] = t.x; g[k][1] = t.y; g[k][2] = t.z; g[k][3] = t.w;
    }

    const int pairs = (nrows + 1) >> 1;
    for (int p = blockIdx.x * 4 + waveInBlk; p < pairs; p += gridDim.x * 4) {
        const int row = p * 2 + half;
        if (row >= nrows) continue;
        const int src = ids[row];
        float4 t = ldf4(emb + (size_t)src * D + col);
        const float* dp = dots + (size_t)row * 6;
        const float c0 = dp[0], c1 = dp[1], c2 = dp[2];
        const float c3 = dp[3], c4 = dp[4], c5 = dp[5];
        float o[4];
        o[0] = 0.5f * A_SCALE * t.x;
        o[1] = 0.5f * A_SCALE * t.y;
        o[2] = 0.5f * A_SCALE * t.z;
        o[3] = 0.5f * A_SCALE * t.w;
#pragma unroll
        for (int j = 0; j < 4; ++j) {
            o[j] = fmaf(c0, g[0][j], o[j]);
            o[j] = fmaf(c1, g[1][j], o[j]);
            o[j] = fmaf(c2, g[2][j], o[j]);
            o[j] = fmaf(c3, g[3][j], o[j]);
            o[j] = fmaf(c4, g[4][j], o[j]);
            o[j] = fmaf(c5, g[5][j], o[j]);
        }
        float4 ov;
        ov.x = o[0]; ov.y = o[1]; ov.z = o[2]; ov.w = o[3];
        *reinterpret_cast<float4*>(out + (size_t)row * D + col) = ov;
    }
}

extern "C" void kernel_launch(void* const* d_in, const int* in_sizes, int n_in,
                              void* d_out, int out_size, void* d_ws, size_t ws_size,
                              hipStream_t stream)
{
    const float* user_emb = (const float*)d_in[0];
    const float* item_emb = (const float*)d_in[1];
    const float* edge_emb = (const float*)d_in[2];
    const float* w_vec    = (const float*)d_in[3];
    const float* w_mat    = (const float*)d_in[4];
    const float* edge_w   = (const float*)d_in[5];
    const int*   user_ids = (const int*)d_in[6];
    const int*   item_ids = (const int*)d_in[7];

    const int U = in_sizes[0] / D;
    const int I = in_sizes[1] / D;

    float* out   = (float*)d_out;
    float* out_x = out;
    float* out_y = out + (size_t)U * D;
    float* out_e = out + (size_t)(U + I) * D;

    const int NB = 1024;   // pass1 grid / partials depth
    float* ws     = (float*)d_ws;
    float* dots_u = ws;                               // U*6
    float* dots_i = dots_u + (size_t)U * 6;           // I*6
    float* part_u = dots_i + (size_t)I * 6;           // 768*NB
    float* part_i = part_u + (size_t)768 * NB;        // 768*NB
    float* R      = part_i + (size_t)768 * NB;        // 12*128
    float* G      = R + 12 * D;                       // 12*128

    pass1_kernel<true ><<<NB, 256, 0, stream>>>(user_emb, user_ids, U, w_vec, edge_emb, dots_u, part_u, NB);
    pass1_kernel<false><<<NB, 256, 0, stream>>>(item_emb, item_ids, I, w_vec, edge_emb, dots_i, part_i, NB);
    combine_kernel<<<384, 256, 0, stream>>>(part_u, part_i, NB, R);
    gmat_kernel<<<15, 128, 0, stream>>>(R, w_mat, edge_w, edge_emb, G, out_e);
    pass2_kernel<<<2048, 256, 0, stream>>>(user_emb, user_ids, U, dots_u, G, out_x);
    pass2_kernel<<<2048, 256, 0, stream>>>(item_emb, item_ids, I, dots_i, G + 6 * D, out_y);
}

// Round 2
// 200.033 us; speedup vs baseline: 1.3031x; 1.3031x over previous
//
#include <hip/hip_runtime.h>
#include <cstddef>

#define D 128

static constexpr float A_SCALE = 0.1f;
static constexpr float B_SCALE = 0.1f;
static constexpr float AB = A_SCALE * B_SCALE;   // fold both scales into dot weights

__device__ __forceinline__ float4 ldf4(const float* p) {
    return *reinterpret_cast<const float4*>(p);
}

// ---------------------------------------------------------------------------
// Pass 1 (merged user+item): per-row dots + global reduction partials.
// Wave layout: 16 lanes x 8 floats per row -> wave = 4 rows/iter.
// Butterfly is 4 levels (within 16-lane group), 9 dots -> 36 DS ops per
// 4 rows (9/row) vs 22.5/row for the 32-lane layout.
// Software pipeline: ids 2-deep, emb 1-deep, so loads stay in flight at
// the 2-waves/SIMD occupancy this kernel's VGPR count allows.
// dots: user dp[b]=a_xx(j0) dp[3+b]=a_xyx(j1); item dp[b]=a_yy(j2) dp[3+b]=a_yxx(j1)
// acc (both sides): k=b pairs d[b][0], k=3+b pairs d[b][2]  (raw-x accumulation,
// A_SCALE applied at partial write).
// partial layout: partial[t][blk], t = k*128+d  (coalesced combine)
// ---------------------------------------------------------------------------
__global__ __launch_bounds__(256) void pass1_kernel(
    const float* __restrict__ ue, const float* __restrict__ ie,
    const int* __restrict__ uids, const int* __restrict__ iids,
    int U, int I, const float* __restrict__ w_vec,
    const float* __restrict__ edge_emb,
    float* __restrict__ dots_u, float* __restrict__ dots_i,
    float* __restrict__ part_u, float* __restrict__ part_i, int nb)
{
    const bool isUser = (int)blockIdx.x < nb;
    const int lb = isUser ? blockIdx.x : (blockIdx.x - nb);
    const float* emb = isUser ? ue : ie;
    const int* ids   = isUser ? uids : iids;
    const int nrows  = isUser ? U : I;
    float* dots      = isUser ? dots_u : dots_i;
    float* partial   = isUser ? part_u : part_i;

    const int lane = threadIdx.x & 63;
    const int grp  = lane >> 4;          // row within quad
    const int li   = lane & 15;
    const int col  = li << 2;            // cols [col,col+4) and [col+64,col+68)
    const int wv_  = threadIdx.x >> 6;   // wave in block

    // ew[b][j][k] = w_vec[b][s][k] * e_raw[k] * A*B  -> dot of raw x gives true dot
    float ew[3][3][8];
    {
        float4 e0 = ldf4(edge_emb + col);
        float4 e1 = ldf4(edge_emb + 64 + col);
        const float ee[8] = {e0.x*AB, e0.y*AB, e0.z*AB, e0.w*AB,
                             e1.x*AB, e1.y*AB, e1.z*AB, e1.w*AB};
#pragma unroll
        for (int b = 0; b < 3; ++b)
#pragma unroll
            for (int j = 0; j < 3; ++j) {
                const int s = isUser ? j : (j + 1);
                float4 w0 = ldf4(w_vec + (b*4+s)*D + col);
                float4 w1 = ldf4(w_vec + (b*4+s)*D + 64 + col);
                ew[b][j][0]=w0.x*ee[0]; ew[b][j][1]=w0.y*ee[1];
                ew[b][j][2]=w0.z*ee[2]; ew[b][j][3]=w0.w*ee[3];
                ew[b][j][4]=w1.x*ee[4]; ew[b][j][5]=w1.y*ee[5];
                ew[b][j][6]=w1.z*ee[6]; ew[b][j][7]=w1.w*ee[7];
            }
    }

    float acc[6][8];
#pragma unroll
    for (int k = 0; k < 6; ++k)
#pragma unroll
        for (int j = 0; j < 8; ++j) acc[k][j] = 0.f;

    const int quads = (nrows + 3) >> 2;
    const int step  = nb * 4;

    int q  = lb * 4 + wv_;
    int rowA = q * 4 + grp;
    bool vA  = (q < quads) && (rowA < nrows);
    int srcA = vA ? ids[rowA] : 0;
    int qB   = q + step;
    int rowB = qB * 4 + grp;
    bool vB  = (qB < quads) && (rowB < nrows);
    int srcB = vB ? ids[rowB] : 0;

    float xA[8];
    {
        const float* p = emb + (size_t)srcA * D;
        float4 t0 = ldf4(p + col);
        float4 t1 = ldf4(p + 64 + col);
        xA[0]=t0.x; xA[1]=t0.y; xA[2]=t0.z; xA[3]=t0.w;
        xA[4]=t1.x; xA[5]=t1.y; xA[6]=t1.z; xA[7]=t1.w;
    }

    while (q < quads) {
        // prefetch ids two iterations ahead, emb one ahead
        const int qC   = qB + step;
        const int rowC = qC * 4 + grp;
        const bool vC  = (qC < quads) && (rowC < nrows);
        const int srcC = vC ? ids[rowC] : 0;
        float xB[8];
        {
            const float* p = emb + (size_t)srcB * D;
            float4 t0 = ldf4(p + col);
            float4 t1 = ldf4(p + 64 + col);
            xB[0]=t0.x; xB[1]=t0.y; xB[2]=t0.z; xB[3]=t0.w;
            xB[4]=t1.x; xB[5]=t1.y; xB[6]=t1.z; xB[7]=t1.w;
        }

        // 9 dots over 8 per-lane elems
        float d[3][3];
#pragma unroll
        for (int b = 0; b < 3; ++b)
#pragma unroll
            for (int j = 0; j < 3; ++j) {
                float s = xA[0] * ew[b][j][0];
#pragma unroll
                for (int k = 1; k < 8; ++k) s = fmaf(xA[k], ew[b][j][k], s);
                d[b][j] = s;
            }
#pragma unroll
        for (int m = 1; m <= 8; m <<= 1) {
#pragma unroll
            for (int b = 0; b < 3; ++b)
#pragma unroll
                for (int j = 0; j < 3; ++j)
                    d[b][j] += __shfl_xor(d[b][j], m, 64);
        }

        const int row = q * 4 + grp;
        if (vA && li == 0) {
            float* dp = dots + (size_t)row * 6;
            if (isUser) {
                dp[0] = d[0][0]; dp[1] = d[1][0]; dp[2] = d[2][0];
                dp[3] = d[0][1]; dp[4] = d[1][1]; dp[5] = d[2][1];
            } else {
                dp[0] = d[0][2]; dp[1] = d[1][2]; dp[2] = d[2][2];
                dp[3] = d[0][1]; dp[4] = d[1][1]; dp[5] = d[2][1];
            }
        }
        if (vA) {
#pragma unroll
            for (int b = 0; b < 3; ++b) {
                const float c0 = d[b][0];
                const float c1 = d[b][2];
#pragma unroll
                for (int j = 0; j < 8; ++j) {
                    acc[b][j]     = fmaf(c0, xA[j], acc[b][j]);
                    acc[3 + b][j] = fmaf(c1, xA[j], acc[3 + b][j]);
                }
            }
        }

        // rotate pipeline
        q = qB; qB = qC;
        vA = vB; vB = vC;
        srcB = srcC;
#pragma unroll
        for (int j = 0; j < 8; ++j) xA[j] = xB[j];
    }

    // cross-group reduce within wave (groups hold same cols, different rows)
#pragma unroll
    for (int k = 0; k < 6; ++k)
#pragma unroll
        for (int j = 0; j < 8; ++j) {
            acc[k][j] += __shfl_xor(acc[k][j], 16, 64);
            acc[k][j] += __shfl_xor(acc[k][j], 32, 64);
        }

    __shared__ float lds[4][6][D];
    if (grp == 0) {
#pragma unroll
        for (int k = 0; k < 6; ++k) {
            float4 v0, v1;
            v0.x=acc[k][0]; v0.y=acc[k][1]; v0.z=acc[k][2]; v0.w=acc[k][3];
            v1.x=acc[k][4]; v1.y=acc[k][5]; v1.z=acc[k][6]; v1.w=acc[k][7];
            *reinterpret_cast<float4*>(&lds[wv_][k][col])      = v0;
            *reinterpret_cast<float4*>(&lds[wv_][k][col + 64]) = v1;
        }
    }
    __syncthreads();
    for (int t = threadIdx.x; t < 6 * D; t += 256) {
        const int k = t >> 7, dd = t & 127;
        const float s = (lds[0][k][dd] + lds[1][k][dd])
                      + (lds[2][k][dd] + lds[3][k][dd]);
        partial[(size_t)t * nb + lb] = s * A_SCALE;
    }
}

// ---------------------------------------------------------------------------
// Combine: one wave per (vector v, dim d); coalesced strided sum over nb
// block partials; fixed-order butterfly -> deterministic.
// R[0..2]=a_xx@x0, R[3..5]=a_yxy@x0, R[6..8]=a_xyy@y0, R[9..11]=a_yy@y0
// ---------------------------------------------------------------------------
__global__ __launch_bounds__(256) void combine_kernel(
    const float* __restrict__ pu, const float* __restrict__ pi, int nb,
    float* __restrict__ R)
{
    const int w = blockIdx.x * 4 + (threadIdx.x >> 6);   // 0..1535
    const int lane = threadIdx.x & 63;
    const int v = w >> 7, dd = w & 127;
    const float* p = (v < 6) ? (pu + (size_t)(v * 128 + dd) * nb)
                             : (pi + (size_t)((v - 6) * 128 + dd) * nb);
    float s = 0.f;
    for (int i = lane; i < nb; i += 64) s += p[i];
#pragma unroll
    for (int m = 1; m <= 32; m <<= 1) s += __shfl_xor(s, m, 64);
    if (lane == 0) R[w] = s;
}

// ---------------------------------------------------------------------------
// gmat: 12 matvecs (R @ w_mat) -> G; 3 edge rows -> d_out tail.
// k split across thread-halves + 4 independent accumulators so the global
// loads pipeline instead of a 128-long serial dependent chain.
// ---------------------------------------------------------------------------
__global__ __launch_bounds__(256) void gmat_kernel(
    const float* __restrict__ R, const float* __restrict__ w_mat,
    const float* __restrict__ edge_w, const float* __restrict__ edge_emb,
    float* __restrict__ G, float* __restrict__ out_edge)
{
    const float mtl[3] = {0.5f, 0.3333333f, 0.1666667f};
    const int blk = blockIdx.x;
    const int d  = threadIdx.x & 127;
    const int kh = threadIdx.x >> 7;     // 0,1 : k-half
    __shared__ float red[2][D];

    if (blk < 12) {
        const int b = blk % 3;
        const int grp = blk / 3;          // 0:G1 1:G2 2:H1 3:H2
        int s, v;
        if      (grp == 0) { s = 0; v = b; }
        else if (grp == 1) { s = 1; v = 6 + b; }
        else if (grp == 2) { s = 3; v = 9 + b; }
        else               { s = 2; v = 3 + b; }
        const float* M = w_mat + ((size_t)(b * 4 + s) * D + kh * 64) * D;
        const float* r = R + v * D + kh * 64;
        float s0 = 0.f, s1 = 0.f, s2 = 0.f, s3 = 0.f;
#pragma unroll
        for (int k = 0; k < 64; k += 4) {
            s0 = fmaf(r[k + 0], M[(size_t)(k + 0) * D + d], s0);
            s1 = fmaf(r[k + 1], M[(size_t)(k + 1) * D + d], s1);
            s2 = fmaf(r[k + 2], M[(size_t)(k + 2) * D + d], s2);
            s3 = fmaf(r[k + 3], M[(size_t)(k + 3) * D + d], s3);
        }
        red[kh][d] = (s0 + s1) + (s2 + s3);
        __syncthreads();
        if (kh == 0)
            G[blk * D + d] = 0.25f * mtl[b] * (red[0][d] + red[1][d]);
    } else {
        const int b = blk - 12;
        const float* M = edge_w + (size_t)b * D * D + (size_t)kh * 64 * D;
        const float* e = edge_emb + kh * 64;
        float s0 = 0.f, s1 = 0.f, s2 = 0.f, s3 = 0.f;
#pragma unroll
        for (int k = 0; k < 64; k += 4) {
            s0 = fmaf(e[k + 0] * B_SCALE, M[(size_t)(k + 0) * D + d], s0);
            s1 = fmaf(e[k + 1] * B_SCALE, M[(size_t)(k + 1) * D + d], s1);
            s2 = fmaf(e[k + 2] * B_SCALE, M[(size_t)(k + 2) * D + d], s2);
            s3 = fmaf(e[k + 3] * B_SCALE, M[(size_t)(k + 3) * D + d], s3);
        }
        red[kh][d] = (s0 + s1) + (s2 + s3);
        __syncthreads();
        if (kh == 0)
            out_edge[b * D + d] =
                0.5f * ((red[0][d] + red[1][d]) + edge_emb[d] * B_SCALE);
    }
}

// ---------------------------------------------------------------------------
// Pass 2 (merged): out[r,:] = 0.5*A*emb[r,:] + sum_k dots[r,k]*G[k][:]
// ---------------------------------------------------------------------------
__global__ __launch_bounds__(256) void pass2_kernel(
    const float* __restrict__ ue, const float* __restrict__ ie,
    const int* __restrict__ uids, const int* __restrict__ iids,
    int U, int I, const float* __restrict__ dots_u,
    const float* __restrict__ dots_i, const float* __restrict__ G,
    float* __restrict__ out, int nbu, int nbi)
{
    const bool isUser = (int)blockIdx.x < nbu;
    const int lb  = isUser ? blockIdx.x : (blockIdx.x - nbu);
    const int nbx = isUser ? nbu : nbi;
    const float* emb  = isUser ? ue : ie;
    const int* ids    = isUser ? uids : iids;
    const int nrows   = isUser ? U : I;
    const float* dots = isUser ? dots_u : dots_i;
    const float* g0   = isUser ? G : (G + 6 * D);
    float* dst        = isUser ? out : (out + (size_t)U * D);

    const int lane = threadIdx.x & 63;
    const int half = lane >> 5;
    const int li   = lane & 31;
    const int col  = li << 2;
    const int waveInBlk = threadIdx.x >> 6;

    float g[6][4];
#pragma unroll
    for (int k = 0; k < 6; ++k) {
        float4 t = ldf4(g0 + k * D + col);
        g[k][0] = t.x; g[k][1] = t.y; g[k][2] = t.z; g[k][3] = t.w;
    }

    const int pairs = (nrows + 1) >> 1;
    for (int p = lb * 4 + waveInBlk; p < pairs; p += nbx * 4) {
        const int row = p * 2 + half;
        if (row >= nrows) continue;
        const int src = ids[row];
        float4 t = ldf4(emb + (size_t)src * D + col);
        const float* dp = dots + (size_t)row * 6;
        const float c0 = dp[0], c1 = dp[1], c2 = dp[2];
        const float c3 = dp[3], c4 = dp[4], c5 = dp[5];
        float o[4];
        o[0] = 0.5f * A_SCALE * t.x;
        o[1] = 0.5f * A_SCALE * t.y;
        o[2] = 0.5f * A_SCALE * t.z;
        o[3] = 0.5f * A_SCALE * t.w;
#pragma unroll
        for (int j = 0; j < 4; ++j) {
            o[j] = fmaf(c0, g[0][j], o[j]);
            o[j] = fmaf(c1, g[1][j], o[j]);
            o[j] = fmaf(c2, g[2][j], o[j]);
            o[j] = fmaf(c3, g[3][j], o[j]);
            o[j] = fmaf(c4, g[4][j], o[j]);
            o[j] = fmaf(c5, g[5][j], o[j]);
        }
        float4 ov;
        ov.x = o[0]; ov.y = o[1]; ov.z = o[2]; ov.w = o[3];
        *reinterpret_cast<float4*>(dst + (size_t)row * D + col) = ov;
    }
}

extern "C" void kernel_launch(void* const* d_in, const int* in_sizes, int n_in,
                              void* d_out, int out_size, void* d_ws, size_t ws_size,
                              hipStream_t stream)
{
    const float* user_emb = (const float*)d_in[0];
    const float* item_emb = (const float*)d_in[1];
    const float* edge_emb = (const float*)d_in[2];
    const float* w_vec    = (const float*)d_in[3];
    const float* w_mat    = (const float*)d_in[4];
    const float* edge_w   = (const float*)d_in[5];
    const int*   user_ids = (const int*)d_in[6];
    const int*   item_ids = (const int*)d_in[7];

    const int U = in_sizes[0] / D;
    const int I = in_sizes[1] / D;

    float* out   = (float*)d_out;
    float* out_e = out + (size_t)(U + I) * D;

    const int NB = 1024;                              // pass1 partial depth/side
    float* ws     = (float*)d_ws;
    float* dots_u = ws;                               // U*6
    float* dots_i = dots_u + (size_t)U * 6;           // I*6
    float* part_u = dots_i + (size_t)I * 6;           // 768*NB
    float* part_i = part_u + (size_t)768 * NB;        // 768*NB
    float* R      = part_i + (size_t)768 * NB;        // 12*128
    float* G      = R + 12 * D;                       // 12*128

    const int NB2U = 1920, NB2I = 1280;

    pass1_kernel<<<2 * NB, 256, 0, stream>>>(
        user_emb, item_emb, user_ids, item_ids, U, I, w_vec, edge_emb,
        dots_u, dots_i, part_u, part_i, NB);
    combine_kernel<<<384, 256, 0, stream>>>(part_u, part_i, NB, R);
    gmat_kernel<<<15, 256, 0, stream>>>(R, w_mat, edge_w, edge_emb, G, out_e);
    pass2_kernel<<<NB2U + NB2I, 256, 0, stream>>>(
        user_emb, item_emb, user_ids, item_ids, U, I, dots_u, dots_i,
        G, out, NB2U, NB2I);
}

// Round 3
// 186.669 us; speedup vs baseline: 1.3964x; 1.0716x over previous
//
#include <hip/hip_runtime.h>
#include <cstddef>

#define D 128

static constexpr float A_SCALE = 0.1f;
static constexpr float B_SCALE = 0.1f;
static constexpr float AB = A_SCALE * B_SCALE;   // fold both scales into dot weights

__device__ __forceinline__ float4 ldf4(const float* p) {
    return *reinterpret_cast<const float4*>(p);
}

// DPP row-rotate fetch: dst[i] = src[(i+N) mod 16] within each 16-lane row.
// ROW_ROR:N ctrl = 0x120+N. Pure VALU (no DS pipe).
template<int CTRL>
__device__ __forceinline__ float dpp_ror(float x) {
    int xi = __builtin_bit_cast(int, x);
    int yi = __builtin_amdgcn_update_dpp(0, xi, CTRL, 0xF, 0xF, true);
    return __builtin_bit_cast(float, yi);
}

// Rotate-allreduce over a 16-lane row: after adding rotations by 1,2,4,8
// every lane holds the 16-lane sum. 8 VALU ops, zero DS ops.
__device__ __forceinline__ float row16_allreduce(float v) {
    v += dpp_ror<0x121>(v);
    v += dpp_ror<0x122>(v);
    v += dpp_ror<0x124>(v);
    v += dpp_ror<0x128>(v);
    return v;
}

// ---------------------------------------------------------------------------
// Pass 1 (merged user+item): per-row dots + global reduction partials.
// Wave layout: 16 lanes x 8 floats per row -> wave = 4 rows/iter.
// Dot reduction: DPP rotate-allreduce (VALU-only; the old shfl butterfly was
// DS-pipe-bound at ~44 us/CU, above the 39 us HBM floor).
// dots: user dp[b]=a_xx(j0) dp[3+b]=a_xyx(j1); item dp[b]=a_yy(j2) dp[3+b]=a_yxx(j1)
// acc: k=b pairs d[b][0], k=3+b pairs d[b][2] (raw-x accumulation, A_SCALE at
// partial write). partial layout: partial[lb][t] (3KB contiguous per block).
// ---------------------------------------------------------------------------
__global__ __launch_bounds__(256) void pass1_kernel(
    const float* __restrict__ ue, const float* __restrict__ ie,
    const int* __restrict__ uids, const int* __restrict__ iids,
    int U, int I, const float* __restrict__ w_vec,
    const float* __restrict__ edge_emb,
    float* __restrict__ dots_u, float* __restrict__ dots_i,
    float* __restrict__ part_u, float* __restrict__ part_i, int nb)
{
    const bool isUser = (int)blockIdx.x < nb;
    const int lb = isUser ? blockIdx.x : (blockIdx.x - nb);
    const float* emb = isUser ? ue : ie;
    const int* ids   = isUser ? uids : iids;
    const int nrows  = isUser ? U : I;
    float* dots      = isUser ? dots_u : dots_i;
    float* partial   = isUser ? part_u : part_i;

    const int lane = threadIdx.x & 63;
    const int grp  = lane >> 4;          // row within quad
    const int li   = lane & 15;
    const int col  = li << 2;            // cols [col,col+4) and [col+64,col+68)
    const int wv_  = threadIdx.x >> 6;   // wave in block

    // ew[b][j][k] = w_vec[b][s][k] * e_raw[k] * A*B
    float ew[3][3][8];
    {
        float4 e0 = ldf4(edge_emb + col);
        float4 e1 = ldf4(edge_emb + 64 + col);
        const float ee[8] = {e0.x*AB, e0.y*AB, e0.z*AB, e0.w*AB,
                             e1.x*AB, e1.y*AB, e1.z*AB, e1.w*AB};
#pragma unroll
        for (int b = 0; b < 3; ++b)
#pragma unroll
            for (int j = 0; j < 3; ++j) {
                const int s = isUser ? j : (j + 1);
                float4 w0 = ldf4(w_vec + (b*4+s)*D + col);
                float4 w1 = ldf4(w_vec + (b*4+s)*D + 64 + col);
                ew[b][j][0]=w0.x*ee[0]; ew[b][j][1]=w0.y*ee[1];
                ew[b][j][2]=w0.z*ee[2]; ew[b][j][3]=w0.w*ee[3];
                ew[b][j][4]=w1.x*ee[4]; ew[b][j][5]=w1.y*ee[5];
                ew[b][j][6]=w1.z*ee[6]; ew[b][j][7]=w1.w*ee[7];
            }
    }

    float acc[6][8];
#pragma unroll
    for (int k = 0; k < 6; ++k)
#pragma unroll
        for (int j = 0; j < 8; ++j) acc[k][j] = 0.f;

    const int quads = (nrows + 3) >> 2;
    const int step  = nb * 4;

    int q  = lb * 4 + wv_;
    int rowA = q * 4 + grp;
    bool vA  = (q < quads) && (rowA < nrows);
    int srcA = vA ? ids[rowA] : 0;
    int qB   = q + step;
    int rowB = qB * 4 + grp;
    bool vB  = (qB < quads) && (rowB < nrows);
    int srcB = vB ? ids[rowB] : 0;

    float xA[8];
    {
        const float* p = emb + (size_t)srcA * D;
        float4 t0 = ldf4(p + col);
        float4 t1 = ldf4(p + 64 + col);
        xA[0]=t0.x; xA[1]=t0.y; xA[2]=t0.z; xA[3]=t0.w;
        xA[4]=t1.x; xA[5]=t1.y; xA[6]=t1.z; xA[7]=t1.w;
    }

    while (q < quads) {
        const int qC   = qB + step;
        const int rowC = qC * 4 + grp;
        const bool vC  = (qC < quads) && (rowC < nrows);
        const int srcC = vC ? ids[rowC] : 0;
        float xB[8];
        {
            const float* p = emb + (size_t)srcB * D;
            float4 t0 = ldf4(p + col);
            float4 t1 = ldf4(p + 64 + col);
            xB[0]=t0.x; xB[1]=t0.y; xB[2]=t0.z; xB[3]=t0.w;
            xB[4]=t1.x; xB[5]=t1.y; xB[6]=t1.z; xB[7]=t1.w;
        }

        // 9 dots over 8 per-lane elems + VALU-only 16-lane allreduce
        float d[3][3];
#pragma unroll
        for (int b = 0; b < 3; ++b)
#pragma unroll
            for (int j = 0; j < 3; ++j) {
                float s = xA[0] * ew[b][j][0];
#pragma unroll
                for (int k = 1; k < 8; ++k) s = fmaf(xA[k], ew[b][j][k], s);
                d[b][j] = row16_allreduce(s);
            }

        const int row = q * 4 + grp;
        if (vA && li == 0) {
            float* dp = dots + (size_t)row * 6;
            if (isUser) {
                dp[0] = d[0][0]; dp[1] = d[1][0]; dp[2] = d[2][0];
                dp[3] = d[0][1]; dp[4] = d[1][1]; dp[5] = d[2][1];
            } else {
                dp[0] = d[0][2]; dp[1] = d[1][2]; dp[2] = d[2][2];
                dp[3] = d[0][1]; dp[4] = d[1][1]; dp[5] = d[2][1];
            }
        }
        if (vA) {
#pragma unroll
            for (int b = 0; b < 3; ++b) {
                const float c0 = d[b][0];
                const float c1 = d[b][2];
#pragma unroll
                for (int j = 0; j < 8; ++j) {
                    acc[b][j]     = fmaf(c0, xA[j], acc[b][j]);
                    acc[3 + b][j] = fmaf(c1, xA[j], acc[3 + b][j]);
                }
            }
        }

        q = qB; qB = qC;
        vA = vB; vB = vC;
        srcB = srcC;
#pragma unroll
        for (int j = 0; j < 8; ++j) xA[j] = xB[j];
    }

    // cross-group reduce within wave (groups hold same cols, different rows)
#pragma unroll
    for (int k = 0; k < 6; ++k)
#pragma unroll
        for (int j = 0; j < 8; ++j) {
            acc[k][j] += __shfl_xor(acc[k][j], 16, 64);
            acc[k][j] += __shfl_xor(acc[k][j], 32, 64);
        }

    __shared__ float lds[4][6][D];
    if (grp == 0) {
#pragma unroll
        for (int k = 0; k < 6; ++k) {
            float4 v0, v1;
            v0.x=acc[k][0]; v0.y=acc[k][1]; v0.z=acc[k][2]; v0.w=acc[k][3];
            v1.x=acc[k][4]; v1.y=acc[k][5]; v1.z=acc[k][6]; v1.w=acc[k][7];
            *reinterpret_cast<float4*>(&lds[wv_][k][col])      = v0;
            *reinterpret_cast<float4*>(&lds[wv_][k][col + 64]) = v1;
        }
    }
    __syncthreads();
    // coalesced: each block owns a contiguous 768-float slab
    float* pp = partial + (size_t)lb * 768;
    for (int t = threadIdx.x; t < 6 * D; t += 256) {
        const int k = t >> 7, dd = t & 127;
        const float s = (lds[0][k][dd] + lds[1][k][dd])
                      + (lds[2][k][dd] + lds[3][k][dd]);
        pp[t] = s * A_SCALE;
    }
}

// ---------------------------------------------------------------------------
// Combine: 48 blocks; block handles 32 consecutive t (one 128B line width).
// Thread (g8, tt) sums lb in {g8, g8+8, ...}; every 128B line of the partial
// buffers is read exactly once. Deterministic fixed-order LDS tree.
// R flat = concat(user 768, item 768) == R[v*128+d] with
// v: 0..2 a_xx@x0, 3..5 a_yxy@x0, 6..8 a_xyy@y0, 9..11 a_yy@y0
// ---------------------------------------------------------------------------
__global__ __launch_bounds__(256) void combine_kernel(
    const float* __restrict__ pu, const float* __restrict__ pi, int nb,
    float* __restrict__ R)
{
    const int T  = blockIdx.x * 32;          // 0..1535 in steps of 32
    const int tt = threadIdx.x & 31;
    const int g8 = threadIdx.x >> 5;         // 0..7
    const float* P;
    int toff;
    if (T < 768) { P = pu; toff = T + tt; }
    else         { P = pi; toff = T - 768 + tt; }

    const int iters = nb >> 3;               // lb = g8 + 8*j
    float s0 = 0.f, s1 = 0.f, s2 = 0.f, s3 = 0.f;
    for (int j = 0; j < iters; j += 4) {
        s0 += P[(size_t)(g8 + 8*(j+0)) * 768 + toff];
        s1 += P[(size_t)(g8 + 8*(j+1)) * 768 + toff];
        s2 += P[(size_t)(g8 + 8*(j+2)) * 768 + toff];
        s3 += P[(size_t)(g8 + 8*(j+3)) * 768 + toff];
    }

    __shared__ float red[8][32];
    red[g8][tt] = (s0 + s1) + (s2 + s3);
    __syncthreads();
    if (threadIdx.x < 32) {
        float s = 0.f;
#pragma unroll
        for (int g = 0; g < 8; ++g) s += red[g][tt];
        R[T + tt] = s;
    }
}

// ---------------------------------------------------------------------------
// gmat: 12 matvecs (R @ w_mat) -> G; 3 edge rows -> d_out tail.
// ---------------------------------------------------------------------------
__global__ __launch_bounds__(256) void gmat_kernel(
    const float* __restrict__ R, const float* __restrict__ w_mat,
    const float* __restrict__ edge_w, const float* __restrict__ edge_emb,
    float* __restrict__ G, float* __restrict__ out_edge)
{
    const float mtl[3] = {0.5f, 0.3333333f, 0.1666667f};
    const int blk = blockIdx.x;
    const int d  = threadIdx.x & 127;
    const int kh = threadIdx.x >> 7;     // 0,1 : k-half
    __shared__ float red[2][D];

    if (blk < 12) {
        const int b = blk % 3;
        const int grp = blk / 3;          // 0:G1 1:G2 2:H1 3:H2
        int s, v;
        if      (grp == 0) { s = 0; v = b; }
        else if (grp == 1) { s = 1; v = 6 + b; }
        else if (grp == 2) { s = 3; v = 9 + b; }
        else               { s = 2; v = 3 + b; }
        const float* M = w_mat + ((size_t)(b * 4 + s) * D + kh * 64) * D;
        const float* r = R + v * D + kh * 64;
        float s0 = 0.f, s1 = 0.f, s2 = 0.f, s3 = 0.f;
#pragma unroll
        for (int k = 0; k < 64; k += 4) {
            s0 = fmaf(r[k + 0], M[(size_t)(k + 0) * D + d], s0);
            s1 = fmaf(r[k + 1], M[(size_t)(k + 1) * D + d], s1);
            s2 = fmaf(r[k + 2], M[(size_t)(k + 2) * D + d], s2);
            s3 = fmaf(r[k + 3], M[(size_t)(k + 3) * D + d], s3);
        }
        red[kh][d] = (s0 + s1) + (s2 + s3);
        __syncthreads();
        if (kh == 0)
            G[blk * D + d] = 0.25f * mtl[b] * (red[0][d] + red[1][d]);
    } else {
        const int b = blk - 12;
        const float* M = edge_w + (size_t)b * D * D + (size_t)kh * 64 * D;
        const float* e = edge_emb + kh * 64;
        float s0 = 0.f, s1 = 0.f, s2 = 0.f, s3 = 0.f;
#pragma unroll
        for (int k = 0; k < 64; k += 4) {
            s0 = fmaf(e[k + 0] * B_SCALE, M[(size_t)(k + 0) * D + d], s0);
            s1 = fmaf(e[k + 1] * B_SCALE, M[(size_t)(k + 1) * D + d], s1);
            s2 = fmaf(e[k + 2] * B_SCALE, M[(size_t)(k + 2) * D + d], s2);
            s3 = fmaf(e[k + 3] * B_SCALE, M[(size_t)(k + 3) * D + d], s3);
        }
        red[kh][d] = (s0 + s1) + (s2 + s3);
        __syncthreads();
        if (kh == 0)
            out_edge[b * D + d] =
                0.5f * ((red[0][d] + red[1][d]) + edge_emb[d] * B_SCALE);
    }
}

// ---------------------------------------------------------------------------
// Pass 2 (merged): out[r,:] = 0.5*A*emb[r,:] + sum_k dots[r,k]*G[k][:]
// ---------------------------------------------------------------------------
__global__ __launch_bounds__(256) void pass2_kernel(
    const float* __restrict__ ue, const float* __restrict__ ie,
    const int* __restrict__ uids, const int* __restrict__ iids,
    int U, int I, const float* __restrict__ dots_u,
    const float* __restrict__ dots_i, const float* __restrict__ G,
    float* __restrict__ out, int nbu, int nbi)
{
    const bool isUser = (int)blockIdx.x < nbu;
    const int lb  = isUser ? blockIdx.x : (blockIdx.x - nbu);
    const int nbx = isUser ? nbu : nbi;
    const float* emb  = isUser ? ue : ie;
    const int* ids    = isUser ? uids : iids;
    const int nrows   = isUser ? U : I;
    const float* dots = isUser ? dots_u : dots_i;
    const float* g0   = isUser ? G : (G + 6 * D);
    float* dst        = isUser ? out : (out + (size_t)U * D);

    const int lane = threadIdx.x & 63;
    const int half = lane >> 5;
    const int li   = lane & 31;
    const int col  = li << 2;
    const int waveInBlk = threadIdx.x >> 6;

    float g[6][4];
#pragma unroll
    for (int k = 0; k < 6; ++k) {
        float4 t = ldf4(g0 + k * D + col);
        g[k][0] = t.x; g[k][1] = t.y; g[k][2] = t.z; g[k][3] = t.w;
    }

    const int pairs = (nrows + 1) >> 1;
    for (int p = lb * 4 + waveInBlk; p < pairs; p += nbx * 4) {
        const int row = p * 2 + half;
        if (row >= nrows) continue;
        const int src = ids[row];
        float4 t = ldf4(emb + (size_t)src * D + col);
        const float* dp = dots + (size_t)row * 6;
        const float c0 = dp[0], c1 = dp[1], c2 = dp[2];
        const float c3 = dp[3], c4 = dp[4], c5 = dp[5];
        float o[4];
        o[0] = 0.5f * A_SCALE * t.x;
        o[1] = 0.5f * A_SCALE * t.y;
        o[2] = 0.5f * A_SCALE * t.z;
        o[3] = 0.5f * A_SCALE * t.w;
#pragma unroll
        for (int j = 0; j < 4; ++j) {
            o[j] = fmaf(c0, g[0][j], o[j]);
            o[j] = fmaf(c1, g[1][j], o[j]);
            o[j] = fmaf(c2, g[2][j], o[j]);
            o[j] = fmaf(c3, g[3][j], o[j]);
            o[j] = fmaf(c4, g[4][j], o[j]);
            o[j] = fmaf(c5, g[5][j], o[j]);
        }
        float4 ov;
        ov.x = o[0]; ov.y = o[1]; ov.z = o[2]; ov.w = o[3];
        *reinterpret_cast<float4*>(dst + (size_t)row * D + col) = ov;
    }
}

extern "C" void kernel_launch(void* const* d_in, const int* in_sizes, int n_in,
                              void* d_out, int out_size, void* d_ws, size_t ws_size,
                              hipStream_t stream)
{
    const float* user_emb = (const float*)d_in[0];
    const float* item_emb = (const float*)d_in[1];
    const float* edge_emb = (const float*)d_in[2];
    const float* w_vec    = (const float*)d_in[3];
    const float* w_mat    = (const float*)d_in[4];
    const float* edge_w   = (const float*)d_in[5];
    const int*   user_ids = (const int*)d_in[6];
    const int*   item_ids = (const int*)d_in[7];

    const int U = in_sizes[0] / D;
    const int I = in_sizes[1] / D;

    float* out   = (float*)d_out;
    float* out_e = out + (size_t)(U + I) * D;

    const int NB = 1024;                              // pass1 partial depth/side
    float* ws     = (float*)d_ws;
    float* dots_u = ws;                               // U*6
    float* dots_i = dots_u + (size_t)U * 6;           // I*6
    float* part_u = dots_i + (size_t)I * 6;           // NB*768
    float* part_i = part_u + (size_t)NB * 768;        // NB*768
    float* R      = part_i + (size_t)NB * 768;        // 12*128
    float* G      = R + 12 * D;                       // 12*128

    const int NB2U = 1920, NB2I = 1280;

    pass1_kernel<<<2 * NB, 256, 0, stream>>>(
        user_emb, item_emb, user_ids, item_ids, U, I, w_vec, edge_emb,
        dots_u, dots_i, part_u, part_i, NB);
    combine_kernel<<<48, 256, 0, stream>>>(part_u, part_i, NB, R);
    gmat_kernel<<<15, 256, 0, stream>>>(R, w_mat, edge_w, edge_emb, G, out_e);
    pass2_kernel<<<NB2U + NB2I, 256, 0, stream>>>(
        user_emb, item_emb, user_ids, item_ids, U, I, dots_u, dots_i,
        G, out, NB2U, NB2I);
}

// Round 5
// 144.142 us; speedup vs baseline: 1.8084x; 1.2950x over previous
//
#include <hip/hip_runtime.h>
#include <cstddef>

#define D 128

static constexpr float A_SCALE = 0.1f;
static constexpr float B_SCALE = 0.1f;
static constexpr float AB = A_SCALE * B_SCALE;   // fold both scales into dot weights

typedef float nfloat4 __attribute__((ext_vector_type(4)));   // native vec for NT builtins

__device__ __forceinline__ float4 ldf4(const float* p) {
    return *reinterpret_cast<const float4*>(p);
}

__device__ __forceinline__ void ntst4(float* p, float a, float b, float c, float d) {
    nfloat4 v; v.x = a; v.y = b; v.z = c; v.w = d;
    __builtin_nontemporal_store(v, reinterpret_cast<nfloat4*>(p));
}

// DPP row-rotate fetch: dst[i] = src[(i+N) mod 16] within each 16-lane row.
// ROW_ROR:N ctrl = 0x120+N. Pure VALU (no DS pipe).
template<int CTRL>
__device__ __forceinline__ float dpp_ror(float x) {
    int xi = __builtin_bit_cast(int, x);
    int yi = __builtin_amdgcn_update_dpp(0, xi, CTRL, 0xF, 0xF, true);
    return __builtin_bit_cast(float, yi);
}

// Rotate-allreduce over a 16-lane row: rotations by 1,2,4,8 -> every lane
// holds the 16-lane sum. 8 VALU ops, zero DS ops.
__device__ __forceinline__ float row16_allreduce(float v) {
    v += dpp_ror<0x121>(v);
    v += dpp_ror<0x122>(v);
    v += dpp_ror<0x124>(v);
    v += dpp_ror<0x128>(v);
    return v;
}

// ---------------------------------------------------------------------------
// Pass 1 (merged user+item): global reduction partials only (dots are
// recomputed in pass 2 -- no dots round-trip).
// Wave layout: 16 lanes x 8 floats per row -> wave = 4 rows/iter. FORWARD
// sweep. 6 dots/4-rows: user s={0,2} (a_xx, a_yxy), item s={1,3} (a_xyy,a_yy).
// acc[b] pairs d[b][0], acc[3+b] pairs d[b][1] (raw-x accumulation, A_SCALE
// applied at partial write). partial layout: partial[lb][t], contiguous 3KB.
// ---------------------------------------------------------------------------
__global__ __launch_bounds__(256) void pass1_kernel(
    const float* __restrict__ ue, const float* __restrict__ ie,
    const int* __restrict__ uids, const int* __restrict__ iids,
    int U, int I, const float* __restrict__ w_vec,
    const float* __restrict__ edge_emb,
    float* __restrict__ part_u, float* __restrict__ part_i, int nb)
{
    const bool isUser = (int)blockIdx.x < nb;
    const int lb = isUser ? blockIdx.x : (blockIdx.x - nb);
    const float* emb = isUser ? ue : ie;
    const int* ids   = isUser ? uids : iids;
    const int nrows  = isUser ? U : I;
    float* partial   = isUser ? part_u : part_i;

    const int lane = threadIdx.x & 63;
    const int grp  = lane >> 4;          // row within quad
    const int li   = lane & 15;
    const int col  = li << 2;            // cols [col,col+4) and [col+64,col+68)
    const int wv_  = threadIdx.x >> 6;   // wave in block

    // ew[b][j][k] = w_vec[b][s][k] * e_raw[k] * A*B
    float ew[3][2][8];
    {
        float4 e0 = ldf4(edge_emb + col);
        float4 e1 = ldf4(edge_emb + 64 + col);
        const float ee[8] = {e0.x*AB, e0.y*AB, e0.z*AB, e0.w*AB,
                             e1.x*AB, e1.y*AB, e1.z*AB, e1.w*AB};
#pragma unroll
        for (int b = 0; b < 3; ++b)
#pragma unroll
            for (int j = 0; j < 2; ++j) {
                const int s = isUser ? (j == 0 ? 0 : 2) : (j == 0 ? 1 : 3);
                float4 w0 = ldf4(w_vec + (b*4+s)*D + col);
                float4 w1 = ldf4(w_vec + (b*4+s)*D + 64 + col);
                ew[b][j][0]=w0.x*ee[0]; ew[b][j][1]=w0.y*ee[1];
                ew[b][j][2]=w0.z*ee[2]; ew[b][j][3]=w0.w*ee[3];
                ew[b][j][4]=w1.x*ee[4]; ew[b][j][5]=w1.y*ee[5];
                ew[b][j][6]=w1.z*ee[6]; ew[b][j][7]=w1.w*ee[7];
            }
    }

    float acc[6][8];
#pragma unroll
    for (int k = 0; k < 6; ++k)
#pragma unroll
        for (int j = 0; j < 8; ++j) acc[k][j] = 0.f;

    const int quads = (nrows + 3) >> 2;
    const int step  = nb * 4;

    int q  = lb * 4 + wv_;
    int rowA = q * 4 + grp;
    bool vA  = (q < quads) && (rowA < nrows);
    int srcA = vA ? ids[rowA] : 0;
    int qB   = q + step;
    int rowB = qB * 4 + grp;
    bool vB  = (qB < quads) && (rowB < nrows);
    int srcB = vB ? ids[rowB] : 0;

    float xA[8];
    {
        const float* p = emb + (size_t)srcA * D;
        float4 t0 = ldf4(p + col);
        float4 t1 = ldf4(p + 64 + col);
        xA[0]=t0.x; xA[1]=t0.y; xA[2]=t0.z; xA[3]=t0.w;
        xA[4]=t1.x; xA[5]=t1.y; xA[6]=t1.z; xA[7]=t1.w;
    }

    while (q < quads) {
        const int qC   = qB + step;
        const int rowC = qC * 4 + grp;
        const bool vC  = (qC < quads) && (rowC < nrows);
        const int srcC = vC ? ids[rowC] : 0;
        float xB[8];
        {
            const float* p = emb + (size_t)srcB * D;
            float4 t0 = ldf4(p + col);
            float4 t1 = ldf4(p + 64 + col);
            xB[0]=t0.x; xB[1]=t0.y; xB[2]=t0.z; xB[3]=t0.w;
            xB[4]=t1.x; xB[5]=t1.y; xB[6]=t1.z; xB[7]=t1.w;
        }

        float d[3][2];
#pragma unroll
        for (int b = 0; b < 3; ++b)
#pragma unroll
            for (int j = 0; j < 2; ++j) {
                float s = xA[0] * ew[b][j][0];
#pragma unroll
                for (int k = 1; k < 8; ++k) s = fmaf(xA[k], ew[b][j][k], s);
                d[b][j] = row16_allreduce(s);
            }

        if (vA) {
#pragma unroll
            for (int b = 0; b < 3; ++b) {
                const float c0 = d[b][0];
                const float c1 = d[b][1];
#pragma unroll
                for (int j = 0; j < 8; ++j) {
                    acc[b][j]     = fmaf(c0, xA[j], acc[b][j]);
                    acc[3 + b][j] = fmaf(c1, xA[j], acc[3 + b][j]);
                }
            }
        }

        q = qB; qB = qC;
        vA = vB; vB = vC;
        srcB = srcC;
#pragma unroll
        for (int j = 0; j < 8; ++j) xA[j] = xB[j];
    }

    // cross-group reduce within wave (groups hold same cols, different rows)
#pragma unroll
    for (int k = 0; k < 6; ++k)
#pragma unroll
        for (int j = 0; j < 8; ++j) {
            acc[k][j] += __shfl_xor(acc[k][j], 16, 64);
            acc[k][j] += __shfl_xor(acc[k][j], 32, 64);
        }

    __shared__ float lds[4][6][D];
    if (grp == 0) {
#pragma unroll
        for (int k = 0; k < 6; ++k) {
            float4 v0, v1;
            v0.x=acc[k][0]; v0.y=acc[k][1]; v0.z=acc[k][2]; v0.w=acc[k][3];
            v1.x=acc[k][4]; v1.y=acc[k][5]; v1.z=acc[k][6]; v1.w=acc[k][7];
            *reinterpret_cast<float4*>(&lds[wv_][k][col])      = v0;
            *reinterpret_cast<float4*>(&lds[wv_][k][col + 64]) = v1;
        }
    }
    __syncthreads();
    float* pp = partial + (size_t)lb * 768;
    for (int t = threadIdx.x; t < 6 * D; t += 256) {
        const int k = t >> 7, dd = t & 127;
        const float s = (lds[0][k][dd] + lds[1][k][dd])
                      + (lds[2][k][dd] + lds[3][k][dd]);
        pp[t] = s * A_SCALE;
    }
}

// ---------------------------------------------------------------------------
// Combine: 48 blocks; block handles 32 consecutive t (one 128B line width).
// Thread (g8, tt) sums lb in {g8, g8+8, ...}; 8 independent accumulators keep
// 8 lines in flight. Deterministic fixed-order LDS tree.
// R: 0..2 a_xx@x0, 3..5 a_yxy@x0, 6..8 a_xyy@y0, 9..11 a_yy@y0
// ---------------------------------------------------------------------------
__global__ __launch_bounds__(256) void combine_kernel(
    const float* __restrict__ pu, const float* __restrict__ pi, int nb,
    float* __restrict__ R)
{
    const int T  = blockIdx.x * 32;          // 0..1535 in steps of 32
    const int tt = threadIdx.x & 31;
    const int g8 = threadIdx.x >> 5;         // 0..7
    const float* P;
    int toff;
    if (T < 768) { P = pu; toff = T + tt; }
    else         { P = pi; toff = T - 768 + tt; }

    const int iters = nb >> 3;               // lb = g8 + 8*j
    float s0=0.f,s1=0.f,s2=0.f,s3=0.f,s4=0.f,s5=0.f,s6=0.f,s7=0.f;
    for (int j = 0; j < iters; j += 8) {
        s0 += P[(size_t)(g8 + 8*(j+0)) * 768 + toff];
        s1 += P[(size_t)(g8 + 8*(j+1)) * 768 + toff];
        s2 += P[(size_t)(g8 + 8*(j+2)) * 768 + toff];
        s3 += P[(size_t)(g8 + 8*(j+3)) * 768 + toff];
        s4 += P[(size_t)(g8 + 8*(j+4)) * 768 + toff];
        s5 += P[(size_t)(g8 + 8*(j+5)) * 768 + toff];
        s6 += P[(size_t)(g8 + 8*(j+6)) * 768 + toff];
        s7 += P[(size_t)(g8 + 8*(j+7)) * 768 + toff];
    }

    __shared__ float red[8][32];
    red[g8][tt] = ((s0 + s1) + (s2 + s3)) + ((s4 + s5) + (s6 + s7));
    __syncthreads();
    if (threadIdx.x < 32) {
        float s = 0.f;
#pragma unroll
        for (int g = 0; g < 8; ++g) s += red[g][tt];
        R[T + tt] = s;
    }
}

// ---------------------------------------------------------------------------
// gmat: 12 matvecs (R @ w_mat) -> G; 3 edge rows -> d_out tail.
// ---------------------------------------------------------------------------
__global__ __launch_bounds__(256) void gmat_kernel(
    const float* __restrict__ R, const float* __restrict__ w_mat,
    const float* __restrict__ edge_w, const float* __restrict__ edge_emb,
    float* __restrict__ G, float* __restrict__ out_edge)
{
    const float mtl[3] = {0.5f, 0.3333333f, 0.1666667f};
    const int blk = blockIdx.x;
    const int d  = threadIdx.x & 127;
    const int kh = threadIdx.x >> 7;     // 0,1 : k-half
    __shared__ float red[2][D];

    if (blk < 12) {
        const int b = blk % 3;
        const int grp = blk / 3;          // 0:G1 1:G2 2:H1 3:H2
        int s, v;
        if      (grp == 0) { s = 0; v = b; }
        else if (grp == 1) { s = 1; v = 6 + b; }
        else if (grp == 2) { s = 3; v = 9 + b; }
        else               { s = 2; v = 3 + b; }
        const float* M = w_mat + ((size_t)(b * 4 + s) * D + kh * 64) * D;
        const float* r = R + v * D + kh * 64;
        float s0 = 0.f, s1 = 0.f, s2 = 0.f, s3 = 0.f;
#pragma unroll
        for (int k = 0; k < 64; k += 4) {
            s0 = fmaf(r[k + 0], M[(size_t)(k + 0) * D + d], s0);
            s1 = fmaf(r[k + 1], M[(size_t)(k + 1) * D + d], s1);
            s2 = fmaf(r[k + 2], M[(size_t)(k + 2) * D + d], s2);
            s3 = fmaf(r[k + 3], M[(size_t)(k + 3) * D + d], s3);
        }
        red[kh][d] = (s0 + s1) + (s2 + s3);
        __syncthreads();
        if (kh == 0)
            G[blk * D + d] = 0.25f * mtl[b] * (red[0][d] + red[1][d]);
    } else {
        const int b = blk - 12;
        const float* M = edge_w + (size_t)b * D * D + (size_t)kh * 64 * D;
        const float* e = edge_emb + kh * 64;
        float s0 = 0.f, s1 = 0.f, s2 = 0.f, s3 = 0.f;
#pragma unroll
        for (int k = 0; k < 64; k += 4) {
            s0 = fmaf(e[k + 0] * B_SCALE, M[(size_t)(k + 0) * D + d], s0);
            s1 = fmaf(e[k + 1] * B_SCALE, M[(size_t)(k + 1) * D + d], s1);
            s2 = fmaf(e[k + 2] * B_SCALE, M[(size_t)(k + 2) * D + d], s2);
            s3 = fmaf(e[k + 3] * B_SCALE, M[(size_t)(k + 3) * D + d], s3);
        }
        red[kh][d] = (s0 + s1) + (s2 + s3);
        __syncthreads();
        if (kh == 0)
            out_edge[b * D + d] =
                0.5f * ((red[0][d] + red[1][d]) + edge_emb[d] * B_SCALE);
    }
}

// ---------------------------------------------------------------------------
// Pass 2 (merged): out[r,:] = 0.5*A*emb[r,:] + sum_b c0[b]*g[b] + c1[b]*g[3+b]
// with c recomputed in-place from the row (no dots buffer). REVERSE sweep
// (boustrophedon: reads pass1's freshest L3 lines first, ends at the head
// where next replay's pass1 begins). Output stores are non-temporal so the
// 256MB stream doesn't evict the embeddings from L3.
// c-dot s-map: user {0,1} (a_xx, a_xyx); item {3,2} (a_yy, a_yxx).
// ---------------------------------------------------------------------------
__global__ __launch_bounds__(256) void pass2_kernel(
    const float* __restrict__ ue, const float* __restrict__ ie,
    const int* __restrict__ uids, const int* __restrict__ iids,
    int U, int I, const float* __restrict__ w_vec,
    const float* __restrict__ edge_emb, const float* __restrict__ G,
    float* __restrict__ out, int nbu, int nbi)
{
    const bool isUser = (int)blockIdx.x < nbu;
    const int lb  = isUser ? blockIdx.x : (blockIdx.x - nbu);
    const int nbx = isUser ? nbu : nbi;
    const float* emb  = isUser ? ue : ie;
    const int* ids    = isUser ? uids : iids;
    const int nrows   = isUser ? U : I;
    const float* g0   = isUser ? G : (G + 6 * D);
    float* dst        = isUser ? out : (out + (size_t)U * D);

    const int lane = threadIdx.x & 63;
    const int grp  = lane >> 4;
    const int li   = lane & 15;
    const int col  = li << 2;
    const int wv_  = threadIdx.x >> 6;

    float ew[3][2][8];
    {
        float4 e0 = ldf4(edge_emb + col);
        float4 e1 = ldf4(edge_emb + 64 + col);
        const float ee[8] = {e0.x*AB, e0.y*AB, e0.z*AB, e0.w*AB,
                             e1.x*AB, e1.y*AB, e1.z*AB, e1.w*AB};
#pragma unroll
        for (int b = 0; b < 3; ++b)
#pragma unroll
            for (int j = 0; j < 2; ++j) {
                const int s = isUser ? (j == 0 ? 0 : 1) : (j == 0 ? 3 : 2);
                float4 w0 = ldf4(w_vec + (b*4+s)*D + col);
                float4 w1 = ldf4(w_vec + (b*4+s)*D + 64 + col);
                ew[b][j][0]=w0.x*ee[0]; ew[b][j][1]=w0.y*ee[1];
                ew[b][j][2]=w0.z*ee[2]; ew[b][j][3]=w0.w*ee[3];
                ew[b][j][4]=w1.x*ee[4]; ew[b][j][5]=w1.y*ee[5];
                ew[b][j][6]=w1.z*ee[6]; ew[b][j][7]=w1.w*ee[7];
            }
    }

    float g[6][8];
#pragma unroll
    for (int k = 0; k < 6; ++k) {
        float4 t0 = ldf4(g0 + k * D + col);
        float4 t1 = ldf4(g0 + k * D + 64 + col);
        g[k][0]=t0.x; g[k][1]=t0.y; g[k][2]=t0.z; g[k][3]=t0.w;
        g[k][4]=t1.x; g[k][5]=t1.y; g[k][6]=t1.z; g[k][7]=t1.w;
    }

    const int quads = (nrows + 3) >> 2;
    const int step  = nbx * 4;

    int ql = lb * 4 + wv_;
    int rA = (quads - 1 - ql) * 4 + grp;
    bool vA = (ql < quads) && (rA < nrows);
    int srcA = vA ? ids[rA] : 0;
    int qlB = ql + step;
    int rB = (quads - 1 - qlB) * 4 + grp;
    bool vB = (qlB < quads) && (rB < nrows);
    int srcB = vB ? ids[rB] : 0;

    float xA[8];
    {
        const float* p = emb + (size_t)srcA * D;
        float4 t0 = ldf4(p + col);
        float4 t1 = ldf4(p + 64 + col);
        xA[0]=t0.x; xA[1]=t0.y; xA[2]=t0.z; xA[3]=t0.w;
        xA[4]=t1.x; xA[5]=t1.y; xA[6]=t1.z; xA[7]=t1.w;
    }

    while (ql < quads) {
        const int qlC = qlB + step;
        const int rC  = (quads - 1 - qlC) * 4 + grp;
        const bool vC = (qlC < quads) && (rC < nrows);
        const int srcC = vC ? ids[rC] : 0;
        float xB[8];
        {
            const float* p = emb + (size_t)srcB * D;
            float4 t0 = ldf4(p + col);
            float4 t1 = ldf4(p + 64 + col);
            xB[0]=t0.x; xB[1]=t0.y; xB[2]=t0.z; xB[3]=t0.w;
            xB[4]=t1.x; xB[5]=t1.y; xB[6]=t1.z; xB[7]=t1.w;
        }

        float d[3][2];
#pragma unroll
        for (int b = 0; b < 3; ++b)
#pragma unroll
            for (int j = 0; j < 2; ++j) {
                float s = xA[0] * ew[b][j][0];
#pragma unroll
                for (int k = 1; k < 8; ++k) s = fmaf(xA[k], ew[b][j][k], s);
                d[b][j] = row16_allreduce(s);
            }

        if (vA) {
            float o[8];
#pragma unroll
            for (int j = 0; j < 8; ++j) o[j] = 0.5f * A_SCALE * xA[j];
#pragma unroll
            for (int b = 0; b < 3; ++b) {
                const float c0 = d[b][0];
                const float c1 = d[b][1];
#pragma unroll
                for (int j = 0; j < 8; ++j) {
                    o[j] = fmaf(c0, g[b][j], o[j]);
                    o[j] = fmaf(c1, g[3 + b][j], o[j]);
                }
            }
            float* op = dst + (size_t)rA * D + col;
            ntst4(op, o[0], o[1], o[2], o[3]);
            ntst4(op + 64, o[4], o[5], o[6], o[7]);
        }

        ql = qlB; qlB = qlC;
        rA = rB; rB = rC;
        vA = vB; vB = vC;
        srcA = srcB; srcB = srcC;
#pragma unroll
        for (int j = 0; j < 8; ++j) xA[j] = xB[j];
    }
}

extern "C" void kernel_launch(void* const* d_in, const int* in_sizes, int n_in,
                              void* d_out, int out_size, void* d_ws, size_t ws_size,
                              hipStream_t stream)
{
    const float* user_emb = (const float*)d_in[0];
    const float* item_emb = (const float*)d_in[1];
    const float* edge_emb = (const float*)d_in[2];
    const float* w_vec    = (const float*)d_in[3];
    const float* w_mat    = (const float*)d_in[4];
    const float* edge_w   = (const float*)d_in[5];
    const int*   user_ids = (const int*)d_in[6];
    const int*   item_ids = (const int*)d_in[7];

    const int U = in_sizes[0] / D;
    const int I = in_sizes[1] / D;

    float* out   = (float*)d_out;
    float* out_e = out + (size_t)(U + I) * D;

    const int NB = 1024;                              // pass1 partial depth/side
    float* ws     = (float*)d_ws;
    float* part_u = ws;                               // NB*768
    float* part_i = part_u + (size_t)NB * 768;        // NB*768
    float* R      = part_i + (size_t)NB * 768;        // 12*128
    float* G      = R + 12 * D;                       // 12*128

    const int NB2U = 1920, NB2I = 1280;

    pass1_kernel<<<2 * NB, 256, 0, stream>>>(
        user_emb, item_emb, user_ids, item_ids, U, I, w_vec, edge_emb,
        part_u, part_i, NB);
    combine_kernel<<<48, 256, 0, stream>>>(part_u, part_i, NB, R);
    gmat_kernel<<<15, 256, 0, stream>>>(R, w_mat, edge_w, edge_emb, G, out_e);
    pass2_kernel<<<NB2U + NB2I, 256, 0, stream>>>(
        user_emb, item_emb, user_ids, item_ids, U, I, w_vec, edge_emb,
        G, out, NB2U, NB2I);
}